// Round 1
// 325.190 us; speedup vs baseline: 1.0196x; 1.0196x over previous
//
#include <hip/hip_runtime.h>

// Two-layer bidirectional LSTM, S=512, B=8192, I=3, H=5.
// R17: unit-per-lane (12 rows/wave, lane = (row r, unit u)), plus:
//  - ws split into per-direction planes (12B rows, 12B stride): layer0's
//    12 rows/wave write one contiguous 144B run per step -> full-sector
//    HBM writes (was 24B interleaved-dir rows, ~2x write inflation).
//  - row stores spread across lanes: layer0 lanes u=0..2 store 1 dword
//    each (1 coalesced store instr, was 3 from one lane); layer1 lanes
//    u=0..4 store their own hu (1 store instr, was dwordx4+dword).
//  - layer1 out-store issues BEFORE the h-bpermute (hu is lane-local),
//    removing the store's dependency on the lgkmcnt(0) wait.
// Carried: fp16 ws rows, fdot2 x-dots, depth-8/4 rotating prefetch,
// sched_barrier after loads, waves_per_eu(1,2).

constexpr int S_ = 512;
constexpr int B_ = 8192;
constexpr int NROW = 16384;    // 2 dirs * 8192

constexpr float L2E  = 1.4426950408889634f;   // log2(e)
constexpr float T2E  = 2.8853900817779268f;   // 2*log2(e)
constexpr float IT2E = 0.34657359027997264f;  // 1/(2*log2(e))

typedef _Float16 v2h __attribute__((ext_vector_type(2)));

__device__ __forceinline__ float dot2h(v2h a, v2h b, float c) {
#if __has_builtin(__builtin_amdgcn_fdot2)
    return __builtin_amdgcn_fdot2(a, b, c, false);
#else
    return fmaf((float)a[0], (float)b[0], fmaf((float)a[1], (float)b[1], c));
#endif
}

__device__ __forceinline__ float rcp_(float x) { return __builtin_amdgcn_rcpf(x); }

__device__ __forceinline__ float exp2_(float x) {
#if __has_builtin(__builtin_amdgcn_exp2f)
    return __builtin_amdgcn_exp2f(x);
#else
    return exp2f(x);
#endif
}

__device__ __forceinline__ void sbar() { __builtin_amdgcn_sched_barrier(0); }

// full-wave backward permute: dst = src[lane bidx/4]
__device__ __forceinline__ float bperm(int bidx, float v) {
    return __int_as_float(__builtin_amdgcn_ds_bpermute(bidx, __float_as_int(v)));
}

__device__ __forceinline__ unsigned pkh(float a, float b) {
    auto t = __builtin_amdgcn_cvt_pkrtz(a, b);   // __fp16 ext_vector(2)
    unsigned q; __builtin_memcpy(&q, &t, 4); return q;
}

// ------- Layer 0: x [S][B][3] f32 -> ws planes [2][S][B] 12B fp16 rows -------
__global__ __launch_bounds__(64) __attribute__((amdgpu_waves_per_eu(1, 2)))
void lstm_layer0(
    const float* __restrict__ x,
    const float* __restrict__ wih_f, const float* __restrict__ whh_f,
    const float* __restrict__ bih_f, const float* __restrict__ bhh_f,
    const float* __restrict__ wih_r, const float* __restrict__ whh_r,
    const float* __restrict__ bih_r, const float* __restrict__ bhh_r,
    unsigned short* __restrict__ ws,
    float* __restrict__ outbase)
{
    const int l64 = threadIdx.x & 63;
    int r = l64 / 5; r = (r > 11) ? 11 : r;     // row-in-wave 0..11
    const int u   = l64 - r * 5;                // 0..4 active (5..8 on idle lanes)
    const int uc  = (u < 5) ? u : 4;
    const int gid = blockIdx.x * 12 + r;
    const bool valid = gid < NROW;
    const int dir = (gid >> 13) & 1;
    const int b   = gid & 8191;
    const bool stw = valid && (u < 3);          // per-lane dword row-store
    const bool st  = valid && (u < 5);          // epilogue-store lanes

    int bidx[5];
#pragma unroll
    for (int k = 0; k < 5; k++) bidx[k] = (r * 5 + k) * 4;

    const float* __restrict__ wih = dir ? wih_r : wih_f;
    const float* __restrict__ whh = dir ? whh_r : whh_f;
    const float* __restrict__ bih = dir ? bih_r : bih_f;
    const float* __restrict__ bhh = dir ? bhh_r : bhh_f;

    // 4 gate rows for unit uc: i,f,g,o = rows uc, 5+uc, 10+uc, 15+uc
    const int rows[4] = {uc, 5 + uc, 10 + uc, 15 + uc};
    const float scl[4] = {-L2E, -L2E, T2E, -L2E};
    float WX[4][3], WH[4][5], BS[4];
#pragma unroll
    for (int gi = 0; gi < 4; gi++) {
        const int rr = rows[gi]; const float sc = scl[gi];
#pragma unroll
        for (int i = 0; i < 3; i++) WX[gi][i] = wih[rr * 3 + i] * sc;
#pragma unroll
        for (int k = 0; k < 5; k++) WH[gi][k] = whh[rr * 5 + k] * sc;
        BS[gi] = (bih[rr] + bhh[rr]) * sc;
    }

    float h[5] = {0.f, 0.f, 0.f, 0.f, 0.f};
    float cp = 0.f, hu_last = 0.f;              // cp = c * 2log2e

    const int t0 = dir ? (S_ - 1) : 0;
    const float* xp = x + ((size_t)t0 * B_ + b) * 3;
    // per-direction plane: rows of 6 shorts (12B), stride 12B
    unsigned short* wp = ws + (size_t)dir * ((size_t)S_ * B_ * 6)
                            + ((size_t)t0 * B_ + b) * 6;
    const ptrdiff_t xst = dir ? -(ptrdiff_t)3 * B_ : (ptrdiff_t)3 * B_;
    const ptrdiff_t wst = dir ? -(ptrdiff_t)6 * B_ : (ptrdiff_t)6 * B_;

    auto step = [&](const float (&xin)[3], unsigned short* wpp) {
        float a0 = BS[0], a1 = BS[1], a2 = BS[2], a3 = BS[3];
#pragma unroll
        for (int i = 0; i < 3; i++) {
            a0 = fmaf(WX[0][i], xin[i], a0);
            a1 = fmaf(WX[1][i], xin[i], a1);
            a2 = fmaf(WX[2][i], xin[i], a2);
            a3 = fmaf(WX[3][i], xin[i], a3);
        }
#pragma unroll
        for (int k = 0; k < 5; k++) {
            a0 = fmaf(WH[0][k], h[k], a0);
            a1 = fmaf(WH[1][k], h[k], a1);
            a2 = fmaf(WH[2][k], h[k], a2);
            a3 = fmaf(WH[3][k], h[k], a3);
        }
        const float ig = rcp_(1.0f + exp2_(a0));                       // sigmoid i
        const float fg = rcp_(1.0f + exp2_(a1));                       // sigmoid f
        const float g2 = fmaf(-2.0f * T2E, rcp_(1.0f + exp2_(a2)), T2E); // 2log2e*tanh g
        const float og = rcp_(1.0f + exp2_(a3));                       // sigmoid o
        cp = fmaf(fg, cp, ig * g2);
        const float th = fmaf(-2.0f, rcp_(1.0f + exp2_(cp)), 1.0f);
        const float hu = og * th;
        hu_last = hu;
#pragma unroll
        for (int k = 0; k < 5; k++) h[k] = bperm(bidx[k], hu);
        // pack + per-lane dword store: lane u (<3) writes dword u of the row
        const unsigned q0 = pkh(h[0], h[1]);
        const unsigned q1 = pkh(h[2], h[3]);
        const unsigned q2 = pkh(h[4], 0.0f);
        unsigned qs = q0;
        qs = (u == 1) ? q1 : qs;
        qs = (u == 2) ? q2 : qs;
        if (stw) ((unsigned*)wpp)[u] = qs;
    };

    auto ld = [&](float (&buf)[3]) {
        __builtin_memcpy(&buf[0], xp, 12);
        xp += xst;
        sbar();
    };

    float x0[3], x1[3], x2[3], x3[3], x4[3], x5[3], x6[3], x7[3];
    ld(x0); ld(x1); ld(x2); ld(x3); ld(x4); ld(x5); ld(x6); ld(x7);

#pragma unroll 1
    for (int s = 0; s < S_ - 8; s += 8) {
        step(x0, wp); wp += wst; ld(x0);
        step(x1, wp); wp += wst; ld(x1);
        step(x2, wp); wp += wst; ld(x2);
        step(x3, wp); wp += wst; ld(x3);
        step(x4, wp); wp += wst; ld(x4);
        step(x5, wp); wp += wst; ld(x5);
        step(x6, wp); wp += wst; ld(x6);
        step(x7, wp); wp += wst; ld(x7);
    }
    step(x0, wp); wp += wst;
    step(x1, wp); wp += wst;
    step(x2, wp); wp += wst;
    step(x3, wp); wp += wst;
    step(x4, wp); wp += wst;
    step(x5, wp); wp += wst;
    step(x6, wp); wp += wst;
    step(x7, wp);

    const size_t OUTE = (size_t)S_ * B_ * 10;
    float* hn = outbase + OUTE + ((size_t)dir * B_ + b) * 5;
    float* cn = hn + (size_t)4 * B_ * 5;
    if (st) { hn[uc] = hu_last; cn[uc] = cp * IT2E; }
}

// ------- Layer 1: ws planes (2 x 12B fp16 rows) -> out [S][B][10] f32 -------
__global__ __launch_bounds__(64) __attribute__((amdgpu_waves_per_eu(1, 2)))
void lstm_layer1(
    const unsigned short* __restrict__ ws,
    const float* __restrict__ wih_f, const float* __restrict__ whh_f,
    const float* __restrict__ bih_f, const float* __restrict__ bhh_f,
    const float* __restrict__ wih_r, const float* __restrict__ whh_r,
    const float* __restrict__ bih_r, const float* __restrict__ bhh_r,
    float* __restrict__ outbase)
{
    const int l64 = threadIdx.x & 63;
    int r = l64 / 5; r = (r > 11) ? 11 : r;
    const int u   = l64 - r * 5;
    const int uc  = (u < 5) ? u : 4;
    const int gid = blockIdx.x * 12 + r;
    const bool valid = gid < NROW;
    const int dir = (gid >> 13) & 1;
    const int b   = gid & 8191;
    const bool st = valid && (u < 5);

    int bidx[5];
#pragma unroll
    for (int k = 0; k < 5; k++) bidx[k] = (r * 5 + k) * 4;

    const float* __restrict__ wih = dir ? wih_r : wih_f;
    const float* __restrict__ whh = dir ? whh_r : whh_f;
    const float* __restrict__ bih = dir ? bih_r : bih_f;
    const float* __restrict__ bhh = dir ? bhh_r : bhh_f;

    const int rows[4] = {uc, 5 + uc, 10 + uc, 15 + uc};
    const float scl[4] = {-L2E, -L2E, T2E, -L2E};
    // x-weights as fp16 pairs matching the two 12B plane rows:
    // fwd plane pairs p=0..2: (w0,w1)(w2,w3)(w4,0)
    // bwd plane pairs p=3..5: (w5,w6)(w7,w8)(w9,0)
    v2h WX[4][6];
    float WH[4][5], BS[4];
#pragma unroll
    for (int gi = 0; gi < 4; gi++) {
        const int rr = rows[gi]; const float sc = scl[gi];
#pragma unroll
        for (int p = 0; p < 6; p++) {
            const int i0 = (p < 3) ? 2 * p : 2 * p - 1;   // 0,2,4,5,7,9
            const bool pad = (p == 2) || (p == 5);
            const float w0 = wih[rr * 10 + i0] * sc;
            const float w1 = pad ? 0.f : wih[rr * 10 + i0 + 1] * sc;
            WX[gi][p] = (v2h){(_Float16)w0, (_Float16)w1};
        }
#pragma unroll
        for (int k = 0; k < 5; k++) WH[gi][k] = whh[rr * 5 + k] * sc;
        BS[gi] = (bih[rr] + bhh[rr]) * sc;
    }

    float h[5] = {0.f, 0.f, 0.f, 0.f, 0.f};
    float cp = 0.f, hu_last = 0.f;

    const int t0 = dir ? (S_ - 1) : 0;
    const unsigned short* rpf = ws + ((size_t)t0 * B_ + b) * 6;
    const unsigned short* rpb = rpf + (size_t)S_ * B_ * 6;
    float* op = outbase + ((size_t)t0 * B_ + b) * 10 + dir * 5;
    const ptrdiff_t rst = dir ? -(ptrdiff_t)6 * B_ : (ptrdiff_t)6 * B_;
    const ptrdiff_t ost = dir ? -(ptrdiff_t)10 * B_ : (ptrdiff_t)10 * B_;

    auto step = [&](const v2h (&xin)[6], float* opp) {
        float a0 = BS[0], a1 = BS[1], a2 = BS[2], a3 = BS[3];
#pragma unroll
        for (int p = 0; p < 6; p++) {
            a0 = dot2h(xin[p], WX[0][p], a0);
            a1 = dot2h(xin[p], WX[1][p], a1);
            a2 = dot2h(xin[p], WX[2][p], a2);
            a3 = dot2h(xin[p], WX[3][p], a3);
        }
#pragma unroll
        for (int k = 0; k < 5; k++) {
            a0 = fmaf(WH[0][k], h[k], a0);
            a1 = fmaf(WH[1][k], h[k], a1);
            a2 = fmaf(WH[2][k], h[k], a2);
            a3 = fmaf(WH[3][k], h[k], a3);
        }
        const float ig = rcp_(1.0f + exp2_(a0));
        const float fg = rcp_(1.0f + exp2_(a1));
        const float g2 = fmaf(-2.0f * T2E, rcp_(1.0f + exp2_(a2)), T2E);
        const float og = rcp_(1.0f + exp2_(a3));
        cp = fmaf(fg, cp, ig * g2);
        const float th = fmaf(-2.0f, rcp_(1.0f + exp2_(cp)), 1.0f);
        const float hu = og * th;
        hu_last = hu;
        // per-lane store BEFORE the bpermute: hu IS h of this lane's unit,
        // so the out-store does not wait on the lgkmcnt(0) broadcast.
        if (st) opp[u] = hu;
#pragma unroll
        for (int k = 0; k < 5; k++) h[k] = bperm(bidx[k], hu);
    };

    auto ld = [&](v2h (&buf)[6]) {
        __builtin_memcpy(&buf[0], rpf, 12);
        __builtin_memcpy(&buf[3], rpb, 12);
        rpf += rst; rpb += rst;
        sbar();
    };

    v2h x0[6], x1[6], x2[6], x3[6];
    ld(x0); ld(x1); ld(x2); ld(x3);

    // main: 127 iterations of 4 -> consumes 0..507, loads 4..511
#pragma unroll 1
    for (int s = 0; s < S_ - 4; s += 4) {
        step(x0, op); op += ost; ld(x0);
        step(x1, op); op += ost; ld(x1);
        step(x2, op); op += ost; ld(x2);
        step(x3, op); op += ost; ld(x3);
    }
    step(x0, op); op += ost;
    step(x1, op); op += ost;
    step(x2, op); op += ost;
    step(x3, op);

    const size_t OUTE = (size_t)S_ * B_ * 10;
    float* hn = outbase + OUTE + ((size_t)(2 + dir) * B_ + b) * 5;
    float* cn = hn + (size_t)4 * B_ * 5;
    if (st) { hn[uc] = hu_last; cn[uc] = cp * IT2E; }
}

extern "C" void kernel_launch(void* const* d_in, const int* in_sizes, int n_in,
                              void* d_out, int out_size, void* d_ws, size_t ws_size,
                              hipStream_t stream) {
    const float* x       = (const float*)d_in[0];
    const float* wih_l0  = (const float*)d_in[1];
    const float* whh_l0  = (const float*)d_in[2];
    const float* bih_l0  = (const float*)d_in[3];
    const float* bhh_l0  = (const float*)d_in[4];
    const float* wih_l0r = (const float*)d_in[5];
    const float* whh_l0r = (const float*)d_in[6];
    const float* bih_l0r = (const float*)d_in[7];
    const float* bhh_l0r = (const float*)d_in[8];
    const float* wih_l1  = (const float*)d_in[9];
    const float* whh_l1  = (const float*)d_in[10];
    const float* bih_l1  = (const float*)d_in[11];
    const float* bhh_l1  = (const float*)d_in[12];
    const float* wih_l1r = (const float*)d_in[13];
    const float* whh_l1r = (const float*)d_in[14];
    const float* bih_l1r = (const float*)d_in[15];
    const float* bhh_l1r = (const float*)d_in[16];

    float* out = (float*)d_out;
    unsigned short* ws = (unsigned short*)d_ws;   // 2 planes * S*B*12B = 100.7 MB

    // 16384 (dir,row) sequences, 12 per 64-lane wave -> 1366 single-wave blocks
    dim3 grid(1366), block(64);
    lstm_layer0<<<grid, block, 0, stream>>>(x,
        wih_l0, whh_l0, bih_l0, bhh_l0,
        wih_l0r, whh_l0r, bih_l0r, bhh_l0r,
        ws, out);
    lstm_layer1<<<grid, block, 0, stream>>>(ws,
        wih_l1, whh_l1, bih_l1, bhh_l1,
        wih_l1r, whh_l1r, bih_l1r, bhh_l1r,
        out);
}